// Round 1
// baseline (3904.958 us; speedup 1.0000x reference)
//
#include <hip/hip_runtime.h>
#include <math.h>

#define B_BATCH 4
#define T_SEQ   2048
#define C_EMB   1024
#define NH      16
#define HS      64

// ---------------------------------------------------------------------------
// SGEMM: C[M,N] = A[M,K] @ B[K,N], row-major fp32.
// BM=BN=128, BK=8, 256 threads, each thread computes an 8x8 micro-tile.
// ---------------------------------------------------------------------------
__global__ __launch_bounds__(256) void sgemm_kernel(const float* __restrict__ A,
                                                    const float* __restrict__ B,
                                                    float* __restrict__ C,
                                                    int M, int N, int K) {
    constexpr int BM = 128, BN = 128, BK = 8;
    __shared__ float As[BK][BM];       // stored transposed: As[k][m]
    __shared__ float Bs[BK][BN];

    const int tid = threadIdx.x;
    const int m0 = blockIdx.y * BM;
    const int n0 = blockIdx.x * BN;

    const int tx = tid & 15;           // 0..15 -> N dir
    const int ty = tid >> 4;           // 0..15 -> M dir

    // A tile load: 128 rows x 8 k, float4: 2 threads/row
    const int a_row = tid >> 1;              // 0..127
    const int a_col = (tid & 1) * 4;         // 0 or 4
    // B tile load: 8 rows x 128 n, float4: 32 threads/row
    const int b_row = tid >> 5;              // 0..7
    const int b_col = (tid & 31) * 4;        // 0..124

    float acc[8][8];
#pragma unroll
    for (int i = 0; i < 8; ++i)
#pragma unroll
        for (int j = 0; j < 8; ++j) acc[i][j] = 0.f;

    for (int k0 = 0; k0 < K; k0 += BK) {
        const float4 av = *(const float4*)(A + (size_t)(m0 + a_row) * K + k0 + a_col);
        const float4 bv = *(const float4*)(B + (size_t)(k0 + b_row) * N + n0 + b_col);
        As[a_col + 0][a_row] = av.x;
        As[a_col + 1][a_row] = av.y;
        As[a_col + 2][a_row] = av.z;
        As[a_col + 3][a_row] = av.w;
        *(float4*)&Bs[b_row][b_col] = bv;
        __syncthreads();

#pragma unroll
        for (int k = 0; k < BK; ++k) {
            const float4 a0 = *(const float4*)&As[k][ty * 8];
            const float4 a1 = *(const float4*)&As[k][ty * 8 + 4];
            const float4 b0 = *(const float4*)&Bs[k][tx * 8];
            const float4 b1 = *(const float4*)&Bs[k][tx * 8 + 4];
            const float a[8] = {a0.x, a0.y, a0.z, a0.w, a1.x, a1.y, a1.z, a1.w};
            const float b[8] = {b0.x, b0.y, b0.z, b0.w, b1.x, b1.y, b1.z, b1.w};
#pragma unroll
            for (int i = 0; i < 8; ++i)
#pragma unroll
                for (int j = 0; j < 8; ++j) acc[i][j] += a[i] * b[j];
        }
        __syncthreads();
    }

#pragma unroll
    for (int i = 0; i < 8; ++i) {
        float* crow = C + (size_t)(m0 + ty * 8 + i) * N + n0 + tx * 8;
        *(float4*)(crow)     = make_float4(acc[i][0], acc[i][1], acc[i][2], acc[i][3]);
        *(float4*)(crow + 4) = make_float4(acc[i][4], acc[i][5], acc[i][6], acc[i][7]);
    }
}

// ---------------------------------------------------------------------------
// Flash-style causal attention, fp32.
// qkv: [B, T, 3C] with q at col 0, k at C, v at 2C; head h = cols h*64..h*64+63.
// y:   [B, T, C]   (heads re-fused)
// grid: (T/64, NH, B); block: 256 threads = 64 rows x 4 segs (16 d-cols each).
// ---------------------------------------------------------------------------
__global__ __launch_bounds__(256) void attn_kernel(const float* __restrict__ qkv,
                                                   float* __restrict__ y) {
    __shared__ float Qs[64][HS];
    __shared__ float Ks[64][HS];
    __shared__ float Vs[64][HS];
    __shared__ float Ss[64][65];   // +1 pad

    const int qt = blockIdx.x;
    const int h  = blockIdx.y;
    const int b  = blockIdx.z;

    const int tid = threadIdx.x;
    const int r   = tid >> 2;      // 0..63 (q row in tile)
    const int seg = tid & 3;       // 0..3  (16-col segment)

    const size_t row_stride = 3 * C_EMB;
    const size_t base = (size_t)b * T_SEQ * row_stride;
    const int q_off = h * HS;
    const int k_off = C_EMB + h * HS;
    const int v_off = 2 * C_EMB + h * HS;
    const int q0 = qt * 64;
    const float scale = 0.125f;    // 1/sqrt(64)

    // load Q tile
#pragma unroll
    for (int j = 0; j < 16; j += 4) {
        *(float4*)&Qs[r][seg * 16 + j] =
            *(const float4*)(qkv + base + (size_t)(q0 + r) * row_stride + q_off + seg * 16 + j);
    }
    __syncthreads();

    // q row into registers (reused across all k-tiles)
    float qreg[HS];
#pragma unroll
    for (int d = 0; d < HS; ++d) qreg[d] = Qs[r][d];

    float o[16];
#pragma unroll
    for (int i = 0; i < 16; ++i) o[i] = 0.f;
    float m = -INFINITY, l = 0.f;

    for (int kt = 0; kt <= qt; ++kt) {
        const int k0 = kt * 64;
        __syncthreads();   // previous iter's Ks/Vs/Ss reads done
#pragma unroll
        for (int j = 0; j < 16; j += 4) {
            *(float4*)&Ks[r][seg * 16 + j] =
                *(const float4*)(qkv + base + (size_t)(k0 + r) * row_stride + k_off + seg * 16 + j);
            *(float4*)&Vs[r][seg * 16 + j] =
                *(const float4*)(qkv + base + (size_t)(k0 + r) * row_stride + v_off + seg * 16 + j);
        }
        __syncthreads();

        // scores: thread computes S[r][seg*16 + j], j=0..15
        float s[16];
#pragma unroll
        for (int j = 0; j < 16; ++j) {
            const int kk = seg * 16 + j;
            float accv = 0.f;
#pragma unroll
            for (int d = 0; d < HS; d += 4) {
                const float4 kv = *(const float4*)&Ks[kk][d];
                accv += qreg[d] * kv.x + qreg[d + 1] * kv.y +
                        qreg[d + 2] * kv.z + qreg[d + 3] * kv.w;
            }
            s[j] = (k0 + kk <= q0 + r) ? accv * scale : -INFINITY;
            Ss[r][kk] = s[j];
        }
        __syncthreads();

        // online softmax stats (each of the 4 threads per row computes redundantly)
        float mt = m;
#pragma unroll 8
        for (int kk = 0; kk < 64; ++kk) mt = fmaxf(mt, Ss[r][kk]);
        float lsum = 0.f;
#pragma unroll 8
        for (int kk = 0; kk < 64; ++kk) lsum += __expf(Ss[r][kk] - mt);
        const float alpha = __expf(m - mt);
        l = l * alpha + lsum;
        m = mt;
        __syncthreads();

        // overwrite own 16 entries with p = exp(s - mt)
#pragma unroll
        for (int j = 0; j < 16; ++j) Ss[r][seg * 16 + j] = __expf(s[j] - mt);
        __syncthreads();

        // O = O*alpha + P @ V  (thread owns 16 d-cols of row r)
#pragma unroll
        for (int i = 0; i < 16; ++i) o[i] *= alpha;
#pragma unroll 4
        for (int kk = 0; kk < 64; ++kk) {
            const float p = Ss[r][kk];
            const float4 v0 = *(const float4*)&Vs[kk][seg * 16 + 0];
            const float4 v1 = *(const float4*)&Vs[kk][seg * 16 + 4];
            const float4 v2 = *(const float4*)&Vs[kk][seg * 16 + 8];
            const float4 v3 = *(const float4*)&Vs[kk][seg * 16 + 12];
            o[0]  += p * v0.x; o[1]  += p * v0.y; o[2]  += p * v0.z; o[3]  += p * v0.w;
            o[4]  += p * v1.x; o[5]  += p * v1.y; o[6]  += p * v1.z; o[7]  += p * v1.w;
            o[8]  += p * v2.x; o[9]  += p * v2.y; o[10] += p * v2.z; o[11] += p * v2.w;
            o[12] += p * v3.x; o[13] += p * v3.y; o[14] += p * v3.z; o[15] += p * v3.w;
        }
    }

    const float inv = 1.f / l;
    float* yrow = y + ((size_t)b * T_SEQ + q0 + r) * C_EMB + h * HS + seg * 16;
#pragma unroll
    for (int j = 0; j < 16; j += 4) {
        *(float4*)(yrow + j) = make_float4(o[j] * inv, o[j + 1] * inv,
                                           o[j + 2] * inv, o[j + 3] * inv);
    }
}

// ---------------------------------------------------------------------------
extern "C" void kernel_launch(void* const* d_in, const int* in_sizes, int n_in,
                              void* d_out, int out_size, void* d_ws, size_t ws_size,
                              hipStream_t stream) {
    const float* x      = (const float*)d_in[0];   // [4,2048,1024]
    const float* w_attn = (const float*)d_in[1];   // [1024,3072]
    const float* w_proj = (const float*)d_in[2];   // [1024,1024]
    float* out = (float*)d_out;                    // [4,2048,1024]

    float* qkv = (float*)d_ws;                         // 8192*3072 fp32 = 96 MB
    float* yv  = qkv + (size_t)8192 * 3072;            // 8192*1024 fp32 = 32 MB

    const int M = B_BATCH * T_SEQ;   // 8192

    // qkv = x @ w_attn
    sgemm_kernel<<<dim3(3 * C_EMB / 128, M / 128), dim3(256), 0, stream>>>(
        x, w_attn, qkv, M, 3 * C_EMB, C_EMB);

    // y = attention(qkv)
    attn_kernel<<<dim3(T_SEQ / 64, NH, B_BATCH), dim3(256), 0, stream>>>(qkv, yv);

    // out = y @ w_proj
    sgemm_kernel<<<dim3(C_EMB / 128, M / 128), dim3(256), 0, stream>>>(
        yv, w_proj, out, M, C_EMB, C_EMB);
}

// Round 2
// 2237.022 us; speedup vs baseline: 1.7456x; 1.7456x over previous
//
#include <hip/hip_runtime.h>
#include <math.h>

#define B_BATCH 4
#define T_SEQ   2048
#define C_EMB   1024
#define NH      16
#define HS      64

// ---------------------------------------------------------------------------
// SGEMM: C[M,N] = A[M,K] @ B[K,N], row-major fp32.  (unchanged: ~95 TF)
// ---------------------------------------------------------------------------
__global__ __launch_bounds__(256) void sgemm_kernel(const float* __restrict__ A,
                                                    const float* __restrict__ B,
                                                    float* __restrict__ C,
                                                    int M, int N, int K) {
    constexpr int BM = 128, BN = 128, BK = 8;
    __shared__ float As[BK][BM];
    __shared__ float Bs[BK][BN];

    const int tid = threadIdx.x;
    const int m0 = blockIdx.y * BM;
    const int n0 = blockIdx.x * BN;

    const int tx = tid & 15;
    const int ty = tid >> 4;

    const int a_row = tid >> 1;
    const int a_col = (tid & 1) * 4;
    const int b_row = tid >> 5;
    const int b_col = (tid & 31) * 4;

    float acc[8][8];
#pragma unroll
    for (int i = 0; i < 8; ++i)
#pragma unroll
        for (int j = 0; j < 8; ++j) acc[i][j] = 0.f;

    for (int k0 = 0; k0 < K; k0 += BK) {
        const float4 av = *(const float4*)(A + (size_t)(m0 + a_row) * K + k0 + a_col);
        const float4 bv = *(const float4*)(B + (size_t)(k0 + b_row) * N + n0 + b_col);
        As[a_col + 0][a_row] = av.x;
        As[a_col + 1][a_row] = av.y;
        As[a_col + 2][a_row] = av.z;
        As[a_col + 3][a_row] = av.w;
        *(float4*)&Bs[b_row][b_col] = bv;
        __syncthreads();

#pragma unroll
        for (int k = 0; k < BK; ++k) {
            const float4 a0 = *(const float4*)&As[k][ty * 8];
            const float4 a1 = *(const float4*)&As[k][ty * 8 + 4];
            const float4 b0 = *(const float4*)&Bs[k][tx * 8];
            const float4 b1 = *(const float4*)&Bs[k][tx * 8 + 4];
            const float a[8] = {a0.x, a0.y, a0.z, a0.w, a1.x, a1.y, a1.z, a1.w};
            const float b[8] = {b0.x, b0.y, b0.z, b0.w, b1.x, b1.y, b1.z, b1.w};
#pragma unroll
            for (int i = 0; i < 8; ++i)
#pragma unroll
                for (int j = 0; j < 8; ++j) acc[i][j] += a[i] * b[j];
        }
        __syncthreads();
    }

#pragma unroll
    for (int i = 0; i < 8; ++i) {
        float* crow = C + (size_t)(m0 + ty * 8 + i) * N + n0 + tx * 8;
        *(float4*)(crow)     = make_float4(acc[i][0], acc[i][1], acc[i][2], acc[i][3]);
        *(float4*)(crow + 4) = make_float4(acc[i][4], acc[i][5], acc[i][6], acc[i][7]);
    }
}

// ---------------------------------------------------------------------------
// Flash attention v2 (fp32, sgemm-shaped stages).
// Per block: 128 q-rows of one (b,h). 256 threads = 16 ty (q) x 16 tx.
// LDS (160 KB dynamic):
//   Qt[64][128]  d-major Q tile (x 1/8 scale), loaded once
//   Kt[64][128]  d-major K tile (per k-tile)
//   Vs[128][64]  row-major V tile (per k-tile)
//   Pt[128][128] k-major P tile (stage1 -> stage2)
// ---------------------------------------------------------------------------
__global__ __launch_bounds__(256, 1) void attn_v2(const float* __restrict__ qkv,
                                                  float* __restrict__ y) {
    extern __shared__ float smem[];
    float* Qt = smem;                   // 64*128
    float* Kt = Qt + 64 * 128;          // 64*128
    float* Vs = Kt + 64 * 128;          // 128*64
    float* Pt = Vs + 128 * 64;          // 128*128

    const int tid = threadIdx.x;
    const int ty  = tid >> 4;           // 0..15  (q micro-row group)
    const int tx  = tid & 15;           // 0..15  (k cols stage1 / d cols stage2)

    const int qt = blockIdx.x;          // q-tile (128 rows)
    const int h  = blockIdx.y;
    const int b  = blockIdx.z;

    const size_t row_stride = 3 * C_EMB;
    const float* qb = qkv + (size_t)b * T_SEQ * row_stride + h * HS;
    const float* kb = qb + C_EMB;
    const float* vb = qb + 2 * C_EMB;

    const int q0 = qt * 128;

    // ---- load Q tile (transposed, scaled) : 8 passes of 16 rows ----
    {
        const int c = tx;               // 16-byte column segment
        const int r = ty;               // row within pass
#pragma unroll
        for (int p = 0; p < 8; ++p) {
            const int qr = p * 16 + r;
            const float4 g = *(const float4*)(qb + (size_t)(q0 + qr) * row_stride + 4 * c);
            Qt[(4 * c + 0) * 128 + qr] = g.x * 0.125f;
            Qt[(4 * c + 1) * 128 + qr] = g.y * 0.125f;
            Qt[(4 * c + 2) * 128 + qr] = g.z * 0.125f;
            Qt[(4 * c + 3) * 128 + qr] = g.w * 0.125f;
        }
    }

    float m8[8], l8[8], alph[8], O[8][4];
#pragma unroll
    for (int i = 0; i < 8; ++i) {
        m8[i] = -1e30f; l8[i] = 0.f;
#pragma unroll
        for (int u = 0; u < 4; ++u) O[i][u] = 0.f;
    }

    for (int kt = 0; kt <= qt; ++kt) {
        const int k0 = kt * 128;
        __syncthreads();   // B1: prev stage2 done reading Vs/Pt

        // ---- load K tile (transposed) + V tile (row-major) ----
        {
            const int c = tx;
            const int r = ty;
#pragma unroll
            for (int p = 0; p < 8; ++p) {
                const int kr = p * 16 + r;
                const float4 g = *(const float4*)(kb + (size_t)(k0 + kr) * row_stride + 4 * c);
                Kt[(4 * c + 0) * 128 + kr] = g.x;
                Kt[(4 * c + 1) * 128 + kr] = g.y;
                Kt[(4 * c + 2) * 128 + kr] = g.z;
                Kt[(4 * c + 3) * 128 + kr] = g.w;
                const float4 gv = *(const float4*)(vb + (size_t)(k0 + kr) * row_stride + 4 * c);
                *(float4*)&Vs[kr * 64 + 4 * c] = gv;
            }
        }
        __syncthreads();   // B2

        // ---- stage 1: S micro-tile 8x8 ----
        float acc[8][8];
#pragma unroll
        for (int i = 0; i < 8; ++i)
#pragma unroll
            for (int j = 0; j < 8; ++j) acc[i][j] = 0.f;

#pragma unroll 8
        for (int d = 0; d < 64; ++d) {
            const float4 a0 = *(const float4*)&Qt[d * 128 + ty * 8];
            const float4 a1 = *(const float4*)&Qt[d * 128 + ty * 8 + 4];
            const float4 b0 = *(const float4*)&Kt[d * 128 + tx * 8];
            const float4 b1 = *(const float4*)&Kt[d * 128 + tx * 8 + 4];
            const float a[8] = {a0.x, a0.y, a0.z, a0.w, a1.x, a1.y, a1.z, a1.w};
            const float bb[8] = {b0.x, b0.y, b0.z, b0.w, b1.x, b1.y, b1.z, b1.w};
#pragma unroll
            for (int i = 0; i < 8; ++i)
#pragma unroll
                for (int j = 0; j < 8; ++j) acc[i][j] += a[i] * bb[j];
        }

        // ---- causal mask (diagonal tile only) ----
        if (kt == qt) {
#pragma unroll
            for (int i = 0; i < 8; ++i)
#pragma unroll
                for (int j = 0; j < 8; ++j)
                    if (tx * 8 + j > ty * 8 + i) acc[i][j] = -1e30f;
        }

        // ---- online softmax stats (shfl over the 16 tx lanes) ----
#pragma unroll
        for (int i = 0; i < 8; ++i) {
            float mx = acc[i][0];
#pragma unroll
            for (int j = 1; j < 8; ++j) mx = fmaxf(mx, acc[i][j]);
            mx = fmaxf(mx, __shfl_xor(mx, 1));
            mx = fmaxf(mx, __shfl_xor(mx, 2));
            mx = fmaxf(mx, __shfl_xor(mx, 4));
            mx = fmaxf(mx, __shfl_xor(mx, 8));
            const float m_new = fmaxf(m8[i], mx);
            alph[i] = __expf(m8[i] - m_new);
            float sm = 0.f;
#pragma unroll
            for (int j = 0; j < 8; ++j) {
                const float p = __expf(acc[i][j] - m_new);
                acc[i][j] = p;
                sm += p;
            }
            sm += __shfl_xor(sm, 1);
            sm += __shfl_xor(sm, 2);
            sm += __shfl_xor(sm, 4);
            sm += __shfl_xor(sm, 8);
            l8[i] = l8[i] * alph[i] + sm;
            m8[i] = m_new;
        }

        // ---- write P transposed: Pt[k][q] ----
#pragma unroll
        for (int j = 0; j < 8; ++j) {
            const int krow = tx * 8 + j;
            *(float4*)&Pt[krow * 128 + ty * 8] =
                make_float4(acc[0][j], acc[1][j], acc[2][j], acc[3][j]);
            *(float4*)&Pt[krow * 128 + ty * 8 + 4] =
                make_float4(acc[4][j], acc[5][j], acc[6][j], acc[7][j]);
        }
        __syncthreads();   // B3

        // ---- stage 2: O = O*alpha + P @ V  (micro 8q x 4d) ----
#pragma unroll
        for (int i = 0; i < 8; ++i)
#pragma unroll
            for (int u = 0; u < 4; ++u) O[i][u] *= alph[i];

#pragma unroll 8
        for (int k = 0; k < 128; ++k) {
            const float4 pA = *(const float4*)&Pt[k * 128 + ty * 8];
            const float4 pB = *(const float4*)&Pt[k * 128 + ty * 8 + 4];
            const float4 v  = *(const float4*)&Vs[k * 64 + tx * 4];
            const float p[8] = {pA.x, pA.y, pA.z, pA.w, pB.x, pB.y, pB.z, pB.w};
#pragma unroll
            for (int i = 0; i < 8; ++i) {
                O[i][0] += p[i] * v.x;
                O[i][1] += p[i] * v.y;
                O[i][2] += p[i] * v.z;
                O[i][3] += p[i] * v.w;
            }
        }
    }

    // ---- epilogue ----
#pragma unroll
    for (int i = 0; i < 8; ++i) {
        const float inv = 1.f / l8[i];
        float* yrow = y + ((size_t)b * T_SEQ + q0 + ty * 8 + i) * C_EMB + h * HS + tx * 4;
        *(float4*)yrow = make_float4(O[i][0] * inv, O[i][1] * inv,
                                     O[i][2] * inv, O[i][3] * inv);
    }
}

// ---------------------------------------------------------------------------
extern "C" void kernel_launch(void* const* d_in, const int* in_sizes, int n_in,
                              void* d_out, int out_size, void* d_ws, size_t ws_size,
                              hipStream_t stream) {
    const float* x      = (const float*)d_in[0];
    const float* w_attn = (const float*)d_in[1];
    const float* w_proj = (const float*)d_in[2];
    float* out = (float*)d_out;

    float* qkv = (float*)d_ws;
    float* yv  = qkv + (size_t)8192 * 3072;

    const int M = B_BATCH * T_SEQ;

    sgemm_kernel<<<dim3(3 * C_EMB / 128, M / 128), dim3(256), 0, stream>>>(
        x, w_attn, qkv, M, 3 * C_EMB, C_EMB);

    static const size_t ATTN_LDS = 160 * 1024;  // 163840 B
    hipFuncSetAttribute((const void*)attn_v2,
                        hipFuncAttributeMaxDynamicSharedMemorySize, (int)ATTN_LDS);
    attn_v2<<<dim3(T_SEQ / 128, NH, B_BATCH), dim3(256), ATTN_LDS, stream>>>(qkv, yv);

    sgemm_kernel<<<dim3(C_EMB / 128, M / 128), dim3(256), 0, stream>>>(
        yv, w_proj, out, M, C_EMB, C_EMB);
}

// Round 3
// 1074.472 us; speedup vs baseline: 3.6343x; 2.0820x over previous
//
#include <hip/hip_runtime.h>
#include <math.h>
#include <stdint.h>

#define B_BATCH 4
#define T_SEQ   2048
#define C_EMB   1024
#define NH      16
#define HS      64

typedef __attribute__((ext_vector_type(8))) short frag8;   // 8 bf16 (4 VGPRs)
typedef __attribute__((ext_vector_type(4))) float f32x4;   // MFMA C/D
typedef __attribute__((ext_vector_type(4))) short short4v; // 8B LDS store

static __device__ __forceinline__ short f2bf(float f) {
    union { float f; uint32_t u; } c; c.f = f;
    uint32_t r = c.u + 0x7fffu + ((c.u >> 16) & 1u);   // RTNE
    return (short)(r >> 16);
}

// ---------------------------------------------------------------------------
// SGEMM: C[M,N] = A[M,K] @ B[K,N], row-major fp32.  (unchanged: ~95 TF)
// ---------------------------------------------------------------------------
__global__ __launch_bounds__(256) void sgemm_kernel(const float* __restrict__ A,
                                                    const float* __restrict__ B,
                                                    float* __restrict__ C,
                                                    int M, int N, int K) {
    constexpr int BM = 128, BN = 128, BK = 8;
    __shared__ float As[BK][BM];
    __shared__ float Bs[BK][BN];

    const int tid = threadIdx.x;
    const int m0 = blockIdx.y * BM;
    const int n0 = blockIdx.x * BN;

    const int tx = tid & 15;
    const int ty = tid >> 4;

    const int a_row = tid >> 1;
    const int a_col = (tid & 1) * 4;
    const int b_row = tid >> 5;
    const int b_col = (tid & 31) * 4;

    float acc[8][8];
#pragma unroll
    for (int i = 0; i < 8; ++i)
#pragma unroll
        for (int j = 0; j < 8; ++j) acc[i][j] = 0.f;

    for (int k0 = 0; k0 < K; k0 += BK) {
        const float4 av = *(const float4*)(A + (size_t)(m0 + a_row) * K + k0 + a_col);
        const float4 bv = *(const float4*)(B + (size_t)(k0 + b_row) * N + n0 + b_col);
        As[a_col + 0][a_row] = av.x;
        As[a_col + 1][a_row] = av.y;
        As[a_col + 2][a_row] = av.z;
        As[a_col + 3][a_row] = av.w;
        *(float4*)&Bs[b_row][b_col] = bv;
        __syncthreads();

#pragma unroll
        for (int k = 0; k < BK; ++k) {
            const float4 a0 = *(const float4*)&As[k][ty * 8];
            const float4 a1 = *(const float4*)&As[k][ty * 8 + 4];
            const float4 b0 = *(const float4*)&Bs[k][tx * 8];
            const float4 b1 = *(const float4*)&Bs[k][tx * 8 + 4];
            const float a[8] = {a0.x, a0.y, a0.z, a0.w, a1.x, a1.y, a1.z, a1.w};
            const float b[8] = {b0.x, b0.y, b0.z, b0.w, b1.x, b1.y, b1.z, b1.w};
#pragma unroll
            for (int i = 0; i < 8; ++i)
#pragma unroll
                for (int j = 0; j < 8; ++j) acc[i][j] += a[i] * b[j];
        }
        __syncthreads();
    }

#pragma unroll
    for (int i = 0; i < 8; ++i) {
        float* crow = C + (size_t)(m0 + ty * 8 + i) * N + n0 + tx * 8;
        *(float4*)(crow)     = make_float4(acc[i][0], acc[i][1], acc[i][2], acc[i][3]);
        *(float4*)(crow + 4) = make_float4(acc[i][4], acc[i][5], acc[i][6], acc[i][7]);
    }
}

// ---------------------------------------------------------------------------
// MFMA flash attention (bf16 inputs, fp32 accumulate).
// Block: 128 q-rows of one (b,h); 256 threads = 4 waves; wave w owns q-rows
// [w*32, w*32+32). Per k-tile (Bc=128):
//   stage1: S^T = K @ Q^T via mfma_f32_16x16x32_bf16 (M=kcol, N=qrow)
//   softmax: per-qrow stats live in C-layout cols; 2 shuffles (xor16,32)
//   P^T(C-layout) -> Pl[qrow][kcol] bf16 (packed b64, wave-private)
//   stage2: O += P @ V (A from Pl, B from Vt = V^T)
// LDS (shorts, all row strides pad +8 => 2-way bank aliasing = free):
//   Kl[128][72], Vt[64][136], Pl[128][136] (also Q staging), stats 1KB.
// Total 71680 B -> 2 blocks/CU.
// ---------------------------------------------------------------------------
#define KL_STRIDE 72
#define VT_STRIDE 136
#define PL_STRIDE 136

__global__ __launch_bounds__(256, 2) void attn_mfma(const float* __restrict__ qkv,
                                                    float* __restrict__ y) {
    extern __shared__ short sm[];
    short* Kl = sm;                       // [128][72]
    short* Vt = sm + 128 * KL_STRIDE;     // [64][136]   (+9216)
    short* Pl = Vt + 64 * VT_STRIDE;      // [128][136]  (+8704)
    float* Astat = (float*)(Pl + 128 * PL_STRIDE);   // [128] alpha, row-indexed
    float* Lstat = Astat + 128;                      // [128] l sums

    const int tid  = threadIdx.x;
    const int wid  = tid >> 6;
    const int lane = tid & 63;
    const int l16  = lane & 15;
    const int quad = lane >> 4;

    const int qt = (T_SEQ / 128 - 1) - blockIdx.x;   // heavy blocks first
    const int h  = blockIdx.y;
    const int b  = blockIdx.z;
    const int q0 = qt * 128;

    const size_t rs = 3 * C_EMB;
    const float* qb = qkv + (size_t)b * T_SEQ * rs + h * HS;
    const float* kb = qb + C_EMB;
    const float* vb = qb + 2 * C_EMB;

    // ---- stage Q (x 1/8) into Pl region, stride 72, then frags -> registers
    {
        const int row  = tid >> 1;
        const int half = tid & 1;
        const float* src = qb + (size_t)(q0 + row) * rs + half * 32;
        short* dst = Pl + row * KL_STRIDE + half * 32;
#pragma unroll
        for (int i = 0; i < 8; ++i) {
            const float4 g = *(const float4*)(src + 4 * i);
            short4v s4 = { f2bf(g.x * 0.125f), f2bf(g.y * 0.125f),
                           f2bf(g.z * 0.125f), f2bf(g.w * 0.125f) };
            *(short4v*)(dst + 4 * i) = s4;
        }
    }
    __syncthreads();

    frag8 aQ[2][2];   // [n-tile][k-step]; serves as B-operand (= Q^T)
#pragma unroll
    for (int nt = 0; nt < 2; ++nt)
#pragma unroll
        for (int s = 0; s < 2; ++s)
            aQ[nt][s] = *(const frag8*)(Pl + (wid * 32 + nt * 16 + l16) * KL_STRIDE +
                                        s * 32 + quad * 8);

    f32x4 O[2][4];    // [q m-tile][d n-tile]
#pragma unroll
    for (int i = 0; i < 2; ++i)
#pragma unroll
        for (int j = 0; j < 4; ++j) O[i][j] = (f32x4){0.f, 0.f, 0.f, 0.f};
    float mw[2] = {-1e30f, -1e30f};
    float lw[2] = {0.f, 0.f};

    for (int kt = 0; kt <= qt; ++kt) {
        const int k0 = kt * 128;
        __syncthreads();   // prior iter's Kl/Vt frag reads done (also covers Q stage)

        // ---- stage K: Kl[kcol][d] ----
        {
            const int row  = tid >> 1;
            const int half = tid & 1;
            const float* src = kb + (size_t)(k0 + row) * rs + half * 32;
            short* dst = Kl + row * KL_STRIDE + half * 32;
#pragma unroll
            for (int i = 0; i < 8; ++i) {
                const float4 g = *(const float4*)(src + 4 * i);
                short4v s4 = { f2bf(g.x), f2bf(g.y), f2bf(g.z), f2bf(g.w) };
                *(short4v*)(dst + 4 * i) = s4;
            }
        }
        // ---- stage V transposed: Vt[d][kcol], paired-row b32 packing ----
        {
            const int rp   = tid & 63;          // rows 2rp, 2rp+1
            const int dblk = tid >> 6;          // d0 = dblk*16
            const float* s0 = vb + (size_t)(k0 + 2 * rp) * rs + dblk * 16;
            const float* s1 = s0 + rs;
#pragma unroll
            for (int u = 0; u < 4; ++u) {
                const float4 a = *(const float4*)(s0 + 4 * u);
                const float4 c = *(const float4*)(s1 + 4 * u);
                const int d0 = dblk * 16 + 4 * u;
                uint32_t w0 = (uint16_t)f2bf(a.x) | ((uint32_t)(uint16_t)f2bf(c.x) << 16);
                uint32_t w1 = (uint16_t)f2bf(a.y) | ((uint32_t)(uint16_t)f2bf(c.y) << 16);
                uint32_t w2 = (uint16_t)f2bf(a.z) | ((uint32_t)(uint16_t)f2bf(c.z) << 16);
                uint32_t w3 = (uint16_t)f2bf(a.w) | ((uint32_t)(uint16_t)f2bf(c.w) << 16);
                *(uint32_t*)(Vt + (d0 + 0) * VT_STRIDE + 2 * rp) = w0;
                *(uint32_t*)(Vt + (d0 + 1) * VT_STRIDE + 2 * rp) = w1;
                *(uint32_t*)(Vt + (d0 + 2) * VT_STRIDE + 2 * rp) = w2;
                *(uint32_t*)(Vt + (d0 + 3) * VT_STRIDE + 2 * rp) = w3;
            }
        }
        __syncthreads();

        // ---- stage 1: S^T = K @ Q^T ----
        f32x4 sacc[8][2];
#pragma unroll
        for (int mt = 0; mt < 8; ++mt)
#pragma unroll
            for (int nt = 0; nt < 2; ++nt) sacc[mt][nt] = (f32x4){0.f, 0.f, 0.f, 0.f};

#pragma unroll
        for (int mt = 0; mt < 8; ++mt) {
            const frag8 aK0 = *(const frag8*)(Kl + (mt * 16 + l16) * KL_STRIDE + quad * 8);
            const frag8 aK1 = *(const frag8*)(Kl + (mt * 16 + l16) * KL_STRIDE + 32 + quad * 8);
#pragma unroll
            for (int nt = 0; nt < 2; ++nt) {
                sacc[mt][nt] = __builtin_amdgcn_mfma_f32_16x16x32_bf16(
                    aK0, aQ[nt][0], sacc[mt][nt], 0, 0, 0);
                sacc[mt][nt] = __builtin_amdgcn_mfma_f32_16x16x32_bf16(
                    aK1, aQ[nt][1], sacc[mt][nt], 0, 0, 0);
            }
        }

        // ---- causal mask (diagonal tile): S^T[kcol][qrow], mask kcol > qrow
        if (kt == qt) {
#pragma unroll
            for (int mt = 0; mt < 8; ++mt)
#pragma unroll
                for (int nt = 0; nt < 2; ++nt) {
                    const int qrow = wid * 32 + nt * 16 + l16;
                    const int kbase = mt * 16 + quad * 4;
#pragma unroll
                    for (int r = 0; r < 4; ++r)
                        if (kbase + r > qrow) sacc[mt][nt][r] = -1e30f;
                }
        }

        // ---- online softmax (per nt; qrow = wid*32 + nt*16 + l16) ----
        float alpha[2];
#pragma unroll
        for (int nt = 0; nt < 2; ++nt) {
            float mx = -1e30f;
#pragma unroll
            for (int mt = 0; mt < 8; ++mt)
#pragma unroll
                for (int r = 0; r < 4; ++r) mx = fmaxf(mx, sacc[mt][nt][r]);
            mx = fmaxf(mx, __shfl_xor(mx, 16));
            mx = fmaxf(mx, __shfl_xor(mx, 32));
            const float mn = fmaxf(mw[nt], mx);
            alpha[nt] = __expf(mw[nt] - mn);
            mw[nt] = mn;

            float ls = 0.f;
            short* prow = Pl + (wid * 32 + nt * 16 + l16) * PL_STRIDE;
#pragma unroll
            for (int mt = 0; mt < 8; ++mt) {
                float p0 = __expf(sacc[mt][nt][0] - mn);
                float p1 = __expf(sacc[mt][nt][1] - mn);
                float p2 = __expf(sacc[mt][nt][2] - mn);
                float p3 = __expf(sacc[mt][nt][3] - mn);
                ls += (p0 + p1) + (p2 + p3);
                short4v s4 = { f2bf(p0), f2bf(p1), f2bf(p2), f2bf(p3) };
                *(short4v*)(prow + mt * 16 + quad * 4) = s4;   // wave-private
            }
            ls += __shfl_xor(ls, 16);
            ls += __shfl_xor(ls, 32);
            lw[nt] = lw[nt] * alpha[nt] + ls;
        }

        // alpha: col-layout -> row-layout via wave-private LDS broadcast
        if (quad == 0) {
            Astat[wid * 32 + l16]      = alpha[0];
            Astat[wid * 32 + 16 + l16] = alpha[1];
        }
        // (wave-internal LDS dependency; compiler inserts lgkmcnt waits)

        // ---- rescale O by per-row alpha ----
#pragma unroll
        for (int mtO = 0; mtO < 2; ++mtO) {
            const int rbase = wid * 32 + mtO * 16 + quad * 4;
            const float a0 = Astat[rbase + 0];
            const float a1 = Astat[rbase + 1];
            const float a2 = Astat[rbase + 2];
            const float a3 = Astat[rbase + 3];
#pragma unroll
            for (int ntO = 0; ntO < 4; ++ntO) {
                O[mtO][ntO][0] *= a0;
                O[mtO][ntO][1] *= a1;
                O[mtO][ntO][2] *= a2;
                O[mtO][ntO][3] *= a3;
            }
        }

        // ---- stage 2: O += P @ V ----
#pragma unroll
        for (int ks = 0; ks < 4; ++ks) {
            frag8 bV[4];
#pragma unroll
            for (int ntO = 0; ntO < 4; ++ntO)
                bV[ntO] = *(const frag8*)(Vt + (ntO * 16 + l16) * VT_STRIDE +
                                          ks * 32 + quad * 8);
#pragma unroll
            for (int mtO = 0; mtO < 2; ++mtO) {
                const frag8 aP = *(const frag8*)(Pl + (wid * 32 + mtO * 16 + l16) * PL_STRIDE +
                                                 ks * 32 + quad * 8);
#pragma unroll
                for (int ntO = 0; ntO < 4; ++ntO)
                    O[mtO][ntO] = __builtin_amdgcn_mfma_f32_16x16x32_bf16(
                        aP, bV[ntO], O[mtO][ntO], 0, 0, 0);
            }
        }
    }

    // ---- epilogue: normalize by 1/l (row-layout via LDS) and store ----
    if (quad == 0) {
        Lstat[wid * 32 + l16]      = lw[0];
        Lstat[wid * 32 + 16 + l16] = lw[1];
    }
#pragma unroll
    for (int mtO = 0; mtO < 2; ++mtO) {
        const int rbase = wid * 32 + mtO * 16 + quad * 4;
#pragma unroll
        for (int r = 0; r < 4; ++r) {
            const float inv = 1.f / Lstat[rbase + r];
            float* yr = y + ((size_t)b * T_SEQ + q0 + rbase + r) * C_EMB + h * HS + l16;
#pragma unroll
            for (int ntO = 0; ntO < 4; ++ntO)
                yr[ntO * 16] = O[mtO][ntO][r] * inv;
        }
    }
}

// ---------------------------------------------------------------------------
extern "C" void kernel_launch(void* const* d_in, const int* in_sizes, int n_in,
                              void* d_out, int out_size, void* d_ws, size_t ws_size,
                              hipStream_t stream) {
    const float* x      = (const float*)d_in[0];
    const float* w_attn = (const float*)d_in[1];
    const float* w_proj = (const float*)d_in[2];
    float* out = (float*)d_out;

    float* qkv = (float*)d_ws;
    float* yv  = qkv + (size_t)8192 * 3072;

    const int M = B_BATCH * T_SEQ;

    sgemm_kernel<<<dim3(3 * C_EMB / 128, M / 128), dim3(256), 0, stream>>>(
        x, w_attn, qkv, M, 3 * C_EMB, C_EMB);

    const size_t ATTN_LDS = (size_t)(128 * KL_STRIDE + 64 * VT_STRIDE + 128 * PL_STRIDE) * 2
                            + 256 * 4;   // 71680 B
    hipFuncSetAttribute((const void*)attn_mfma,
                        hipFuncAttributeMaxDynamicSharedMemorySize, (int)ATTN_LDS);
    attn_mfma<<<dim3(T_SEQ / 128, NH, B_BATCH), dim3(256), ATTN_LDS, stream>>>(qkv, yv);

    sgemm_kernel<<<dim3(C_EMB / 128, M / 128), dim3(256), 0, stream>>>(
        yv, w_proj, out, M, C_EMB, C_EMB);
}

// Round 4
// 337.893 us; speedup vs baseline: 11.5568x; 3.1799x over previous
//
#include <hip/hip_runtime.h>
#include <math.h>
#include <stdint.h>

#define B_BATCH 4
#define T_SEQ   2048
#define C_EMB   1024
#define NH      16
#define HS      64

typedef __attribute__((ext_vector_type(8))) short frag8;   // 8 bf16 (4 VGPRs)
typedef __attribute__((ext_vector_type(4))) float f32x4;   // MFMA C/D
typedef __attribute__((ext_vector_type(4))) short short4v; // 8B
typedef __attribute__((ext_vector_type(8))) short short8v; // 16B
typedef __attribute__((ext_vector_type(4))) unsigned short us4;

static __device__ __forceinline__ short f2bf(float f) {
    union { float f; uint32_t u; } c; c.f = f;
    uint32_t r = c.u + 0x7fffu + ((c.u >> 16) & 1u);   // RTNE
    return (short)(r >> 16);
}

// async global->LDS, 16B per lane; lds dest = wave-uniform base + lane*16
static __device__ __forceinline__ void stage16(const void* g, void* lds_base) {
#if __has_builtin(__builtin_amdgcn_global_load_lds)
    __builtin_amdgcn_global_load_lds(
        (const __attribute__((address_space(1))) void*)g,
        (__attribute__((address_space(3))) void*)lds_base, 16, 0, 0);
#else
    const int lane = threadIdx.x & 63;
    ((uint4*)lds_base)[lane] = *(const uint4*)g;
#endif
}

// ---------------------------------------------------------------------------
// fp32 -> bf16 elementwise (8 elems/thread)
// ---------------------------------------------------------------------------
__global__ __launch_bounds__(256) void f32_to_bf16(const float* __restrict__ src,
                                                   short* __restrict__ dst, int n8) {
    const int i = blockIdx.x * 256 + threadIdx.x;
    if (i >= n8) return;
    const float4 a = *(const float4*)(src + (size_t)i * 8);
    const float4 b = *(const float4*)(src + (size_t)i * 8 + 4);
    short8v s = { f2bf(a.x), f2bf(a.y), f2bf(a.z), f2bf(a.w),
                  f2bf(b.x), f2bf(b.y), f2bf(b.z), f2bf(b.w) };
    *(short8v*)(dst + (size_t)i * 8) = s;
}

// ---------------------------------------------------------------------------
// W[K][N] fp32 -> WT[N][K] bf16, 64x64 LDS tile
// ---------------------------------------------------------------------------
__global__ __launch_bounds__(256) void transpose_f32_bf16(const float* __restrict__ W,
                                                          short* __restrict__ WT,
                                                          int K, int N) {
    __shared__ float t[64][65];
    const int k0 = blockIdx.y * 64, n0 = blockIdx.x * 64;
    const int tid = threadIdx.x;
    const int r = tid >> 4, c4 = (tid & 15) * 4;
#pragma unroll
    for (int p = 0; p < 4; ++p) {
        const float4 g = *(const float4*)(W + (size_t)(k0 + p * 16 + r) * N + n0 + c4);
        t[p * 16 + r][c4 + 0] = g.x;
        t[p * 16 + r][c4 + 1] = g.y;
        t[p * 16 + r][c4 + 2] = g.z;
        t[p * 16 + r][c4 + 3] = g.w;
    }
    __syncthreads();
#pragma unroll
    for (int p = 0; p < 4; ++p) {
        const int n = p * 16 + r;
        short4v s = { f2bf(t[c4 + 0][n]), f2bf(t[c4 + 1][n]),
                      f2bf(t[c4 + 2][n]), f2bf(t[c4 + 3][n]) };
        *(short4v*)(WT + (size_t)(n0 + n) * K + k0 + c4) = s;
    }
}

// ---------------------------------------------------------------------------
// bf16 MFMA GEMM (m97 structure): C[M,N] = A[M,K] @ Bt[N,K]^T
// 128x128 tile, BK=32, 4 waves, wave = 64x64 (4x4 of 16x16x32 MFMA).
// Staging via global_load_lds width=16 into unpadded [128][32] tiles.
// ---------------------------------------------------------------------------
template <bool OUT_BF16>
__global__ __launch_bounds__(256) void gemm_bt(const short* __restrict__ A,
                                               const short* __restrict__ Bt,
                                               void* __restrict__ Cout,
                                               int M, int N, int K) {
    __shared__ short As[128 * 32];
    __shared__ short Bs[128 * 32];

    const int tid  = threadIdx.x;
    const int lane = tid & 63;
    const int wid  = tid >> 6;
    const int l16  = lane & 15;
    const int quad = lane >> 4;

    const int m0 = blockIdx.y * 128;
    const int n0 = blockIdx.x * 128;
    const int wm = (wid >> 1) * 64;
    const int wn = (wid & 1) * 64;

    const short* gA0 = A  + (size_t)(m0 + wid * 16      + (lane >> 2)) * K + (lane & 3) * 8;
    const short* gA1 = A  + (size_t)(m0 + wid * 16 + 64 + (lane >> 2)) * K + (lane & 3) * 8;
    const short* gB0 = Bt + (size_t)(n0 + wid * 16      + (lane >> 2)) * K + (lane & 3) * 8;
    const short* gB1 = Bt + (size_t)(n0 + wid * 16 + 64 + (lane >> 2)) * K + (lane & 3) * 8;

    short* lA0 = As + (size_t)wid * 512;        // wave-uniform chunk bases
    short* lA1 = As + (size_t)(wid + 4) * 512;
    short* lB0 = Bs + (size_t)wid * 512;
    short* lB1 = Bs + (size_t)(wid + 4) * 512;

    f32x4 acc[4][4];
#pragma unroll
    for (int i = 0; i < 4; ++i)
#pragma unroll
        for (int j = 0; j < 4; ++j) acc[i][j] = (f32x4){0.f, 0.f, 0.f, 0.f};

    for (int k0 = 0; k0 < K; k0 += 32) {
        __syncthreads();                        // prior frag reads done
        stage16(gA0 + k0, lA0);
        stage16(gA1 + k0, lA1);
        stage16(gB0 + k0, lB0);
        stage16(gB1 + k0, lB1);
        __syncthreads();                        // drains vmcnt before barrier

        frag8 fa[4], fb[4];
#pragma unroll
        for (int mt = 0; mt < 4; ++mt)
            fa[mt] = *(const frag8*)(As + (wm + mt * 16 + l16) * 32 + quad * 8);
#pragma unroll
        for (int nt = 0; nt < 4; ++nt)
            fb[nt] = *(const frag8*)(Bs + (wn + nt * 16 + l16) * 32 + quad * 8);
#pragma unroll
        for (int mt = 0; mt < 4; ++mt)
#pragma unroll
            for (int nt = 0; nt < 4; ++nt)
                acc[mt][nt] = __builtin_amdgcn_mfma_f32_16x16x32_bf16(
                    fa[mt], fb[nt], acc[mt][nt], 0, 0, 0);
    }

#pragma unroll
    for (int mt = 0; mt < 4; ++mt)
#pragma unroll
        for (int nt = 0; nt < 4; ++nt)
#pragma unroll
            for (int r = 0; r < 4; ++r) {
                const size_t row = m0 + wm + mt * 16 + quad * 4 + r;
                const size_t col = n0 + wn + nt * 16 + l16;
                if constexpr (OUT_BF16)
                    ((short*)Cout)[row * N + col] = f2bf(acc[mt][nt][r]);
                else
                    ((float*)Cout)[row * N + col] = acc[mt][nt][r];
            }
}

// ---------------------------------------------------------------------------
// MFMA flash attention, bf16 qkv in, bf16 y out. (structure from round 3)
// ---------------------------------------------------------------------------
#define KL_STRIDE 72
#define VT_STRIDE 136
#define PL_STRIDE 136

__global__ __launch_bounds__(256, 2) void attn_mfma(const short* __restrict__ qkv,
                                                    short* __restrict__ y) {
    extern __shared__ short sm[];
    short* Kl = sm;                        // [128][72]
    short* Vt = sm + 128 * KL_STRIDE;      // [64][136]
    short* Pl = Vt + 64 * VT_STRIDE;       // [128][136]  (Q staging at stride 72)
    float* Astat = (float*)(Pl + 128 * PL_STRIDE);
    float* Lstat = Astat + 128;

    const int tid  = threadIdx.x;
    const int wid  = tid >> 6;
    const int lane = tid & 63;
    const int l16  = lane & 15;
    const int quad = lane >> 4;

    const int qt = (T_SEQ / 128 - 1) - blockIdx.x;
    const int h  = blockIdx.y;
    const int b  = blockIdx.z;
    const int q0 = qt * 128;

    const size_t rs = 3 * C_EMB;
    const short* qb = qkv + (size_t)b * T_SEQ * rs + h * HS;
    const short* kb = qb + C_EMB;
    const short* vb = qb + 2 * C_EMB;

    // ---- stage Q (plain copy, scale folded into S later) ----
    {
        const int row  = tid >> 1;
        const int half = tid & 1;
        const short* src = qb + (size_t)(q0 + row) * rs + half * 32;
        short* dst = Pl + row * KL_STRIDE + half * 32;
#pragma unroll
        for (int i = 0; i < 4; ++i)
            *(short8v*)(dst + 8 * i) = *(const short8v*)(src + 8 * i);
    }
    __syncthreads();

    frag8 aQ[2][2];
#pragma unroll
    for (int nt = 0; nt < 2; ++nt)
#pragma unroll
        for (int s = 0; s < 2; ++s)
            aQ[nt][s] = *(const frag8*)(Pl + (wid * 32 + nt * 16 + l16) * KL_STRIDE +
                                        s * 32 + quad * 8);

    f32x4 O[2][4];
#pragma unroll
    for (int i = 0; i < 2; ++i)
#pragma unroll
        for (int j = 0; j < 4; ++j) O[i][j] = (f32x4){0.f, 0.f, 0.f, 0.f};
    float mw[2] = {-1e30f, -1e30f};
    float lw[2] = {0.f, 0.f};

    for (int kt = 0; kt <= qt; ++kt) {
        const int k0 = kt * 128;
        __syncthreads();

        // ---- stage K (plain copy) ----
        {
            const int row  = tid >> 1;
            const int half = tid & 1;
            const short* src = kb + (size_t)(k0 + row) * rs + half * 32;
            short* dst = Kl + row * KL_STRIDE + half * 32;
#pragma unroll
            for (int i = 0; i < 4; ++i)
                *(short8v*)(dst + 8 * i) = *(const short8v*)(src + 8 * i);
        }
        // ---- stage V transposed: Vt[d][kcol], paired-row b32 packing ----
        {
            const int rp   = tid & 63;
            const int dblk = tid >> 6;
            const short* s0 = vb + (size_t)(k0 + 2 * rp) * rs + dblk * 16;
            const short* s1 = s0 + rs;
#pragma unroll
            for (int u = 0; u < 4; ++u) {
                const us4 a = *(const us4*)(s0 + 4 * u);
                const us4 c = *(const us4*)(s1 + 4 * u);
                const int d0 = dblk * 16 + 4 * u;
                uint32_t w0 = (uint32_t)a.x | ((uint32_t)c.x << 16);
                uint32_t w1 = (uint32_t)a.y | ((uint32_t)c.y << 16);
                uint32_t w2 = (uint32_t)a.z | ((uint32_t)c.z << 16);
                uint32_t w3 = (uint32_t)a.w | ((uint32_t)c.w << 16);
                *(uint32_t*)(Vt + (d0 + 0) * VT_STRIDE + 2 * rp) = w0;
                *(uint32_t*)(Vt + (d0 + 1) * VT_STRIDE + 2 * rp) = w1;
                *(uint32_t*)(Vt + (d0 + 2) * VT_STRIDE + 2 * rp) = w2;
                *(uint32_t*)(Vt + (d0 + 3) * VT_STRIDE + 2 * rp) = w3;
            }
        }
        __syncthreads();

        // ---- stage 1: S^T = K @ Q^T ----
        f32x4 sacc[8][2];
#pragma unroll
        for (int mt = 0; mt < 8; ++mt)
#pragma unroll
            for (int nt = 0; nt < 2; ++nt) sacc[mt][nt] = (f32x4){0.f, 0.f, 0.f, 0.f};

#pragma unroll
        for (int mt = 0; mt < 8; ++mt) {
            const frag8 aK0 = *(const frag8*)(Kl + (mt * 16 + l16) * KL_STRIDE + quad * 8);
            const frag8 aK1 = *(const frag8*)(Kl + (mt * 16 + l16) * KL_STRIDE + 32 + quad * 8);
#pragma unroll
            for (int nt = 0; nt < 2; ++nt) {
                sacc[mt][nt] = __builtin_amdgcn_mfma_f32_16x16x32_bf16(
                    aK0, aQ[nt][0], sacc[mt][nt], 0, 0, 0);
                sacc[mt][nt] = __builtin_amdgcn_mfma_f32_16x16x32_bf16(
                    aK1, aQ[nt][1], sacc[mt][nt], 0, 0, 0);
            }
        }

        // ---- scale by 1/sqrt(hs) in fp32 ----
#pragma unroll
        for (int mt = 0; mt < 8; ++mt)
#pragma unroll
            for (int nt = 0; nt < 2; ++nt) sacc[mt][nt] *= 0.125f;

        // ---- causal mask (diagonal tile) ----
        if (kt == qt) {
#pragma unroll
            for (int mt = 0; mt < 8; ++mt)
#pragma unroll
                for (int nt = 0; nt < 2; ++nt) {
                    const int qrow = wid * 32 + nt * 16 + l16;
                    const int kbase = mt * 16 + quad * 4;
#pragma unroll
                    for (int r = 0; r < 4; ++r)
                        if (kbase + r > qrow) sacc[mt][nt][r] = -1e30f;
                }
        }

        // ---- online softmax ----
        float alpha[2];
#pragma unroll
        for (int nt = 0; nt < 2; ++nt) {
            float mx = -1e30f;
#pragma unroll
            for (int mt = 0; mt < 8; ++mt)
#pragma unroll
                for (int r = 0; r < 4; ++r) mx = fmaxf(mx, sacc[mt][nt][r]);
            mx = fmaxf(mx, __shfl_xor(mx, 16));
            mx = fmaxf(mx, __shfl_xor(mx, 32));
            const float mn = fmaxf(mw[nt], mx);
            alpha[nt] = __expf(mw[nt] - mn);
            mw[nt] = mn;

            float ls = 0.f;
            short* prow = Pl + (wid * 32 + nt * 16 + l16) * PL_STRIDE;
#pragma unroll
            for (int mt = 0; mt < 8; ++mt) {
                float p0 = __expf(sacc[mt][nt][0] - mn);
                float p1 = __expf(sacc[mt][nt][1] - mn);
                float p2 = __expf(sacc[mt][nt][2] - mn);
                float p3 = __expf(sacc[mt][nt][3] - mn);
                ls += (p0 + p1) + (p2 + p3);
                short4v s4 = { f2bf(p0), f2bf(p1), f2bf(p2), f2bf(p3) };
                *(short4v*)(prow + mt * 16 + quad * 4) = s4;
            }
            ls += __shfl_xor(ls, 16);
            ls += __shfl_xor(ls, 32);
            lw[nt] = lw[nt] * alpha[nt] + ls;
        }

        if (quad == 0) {
            Astat[wid * 32 + l16]      = alpha[0];
            Astat[wid * 32 + 16 + l16] = alpha[1];
        }

#pragma unroll
        for (int mtO = 0; mtO < 2; ++mtO) {
            const int rbase = wid * 32 + mtO * 16 + quad * 4;
            const float a0 = Astat[rbase + 0];
            const float a1 = Astat[rbase + 1];
            const float a2 = Astat[rbase + 2];
            const float a3 = Astat[rbase + 3];
#pragma unroll
            for (int ntO = 0; ntO < 4; ++ntO) {
                O[mtO][ntO][0] *= a0;
                O[mtO][ntO][1] *= a1;
                O[mtO][ntO][2] *= a2;
                O[mtO][ntO][3] *= a3;
            }
        }

        // ---- stage 2: O += P @ V ----
#pragma unroll
        for (int ks = 0; ks < 4; ++ks) {
            frag8 bV[4];
#pragma unroll
            for (int ntO = 0; ntO < 4; ++ntO)
                bV[ntO] = *(const frag8*)(Vt + (ntO * 16 + l16) * VT_STRIDE +
                                          ks * 32 + quad * 8);
#pragma unroll
            for (int mtO = 0; mtO < 2; ++mtO) {
                const frag8 aP = *(const frag8*)(Pl + (wid * 32 + mtO * 16 + l16) * PL_STRIDE +
                                                 ks * 32 + quad * 8);
#pragma unroll
                for (int ntO = 0; ntO < 4; ++ntO)
                    O[mtO][ntO] = __builtin_amdgcn_mfma_f32_16x16x32_bf16(
                        aP, bV[ntO], O[mtO][ntO], 0, 0, 0);
            }
        }
    }

    // ---- epilogue: y (bf16) ----
    if (quad == 0) {
        Lstat[wid * 32 + l16]      = lw[0];
        Lstat[wid * 32 + 16 + l16] = lw[1];
    }
#pragma unroll
    for (int mtO = 0; mtO < 2; ++mtO) {
        const int rbase = wid * 32 + mtO * 16 + quad * 4;
#pragma unroll
        for (int r = 0; r < 4; ++r) {
            const float inv = 1.f / Lstat[rbase + r];
            short* yr = y + ((size_t)b * T_SEQ + q0 + rbase + r) * C_EMB + h * HS + l16;
#pragma unroll
            for (int ntO = 0; ntO < 4; ++ntO)
                yr[ntO * 16] = f2bf(O[mtO][ntO][r] * inv);
        }
    }
}

// ---------------------------------------------------------------------------
extern "C" void kernel_launch(void* const* d_in, const int* in_sizes, int n_in,
                              void* d_out, int out_size, void* d_ws, size_t ws_size,
                              hipStream_t stream) {
    const float* x      = (const float*)d_in[0];   // [8192,1024]
    const float* w_attn = (const float*)d_in[1];   // [1024,3072]
    const float* w_proj = (const float*)d_in[2];   // [1024,1024]
    float* out = (float*)d_out;

    short* xb   = (short*)d_ws;                          // 16 MB
    short* waT  = xb   + (size_t)8192 * 1024;            //  6 MB [3072][1024]
    short* wpT  = waT  + (size_t)3072 * 1024;            //  2 MB [1024][1024]
    short* qkvb = wpT  + (size_t)1024 * 1024;            // 48 MB [8192][3072]
    short* yb   = qkvb + (size_t)8192 * 3072;            // 16 MB [8192][1024]

    // pre-passes: fp32 -> bf16 (+ weight transpose)
    f32_to_bf16<<<4096, 256, 0, stream>>>(x, xb, 8192 * 1024 / 8);
    transpose_f32_bf16<<<dim3(48, 16), 256, 0, stream>>>(w_attn, waT, 1024, 3072);
    transpose_f32_bf16<<<dim3(16, 16), 256, 0, stream>>>(w_proj, wpT, 1024, 1024);

    // qkv = x @ w_attn   (bf16 out)
    gemm_bt<true><<<dim3(24, 64), 256, 0, stream>>>(xb, waT, qkvb, 8192, 3072, 1024);

    // attention
    const size_t ATTN_LDS = (size_t)(128 * KL_STRIDE + 64 * VT_STRIDE + 128 * PL_STRIDE) * 2
                            + 256 * 4;   // 71680 B
    hipFuncSetAttribute((const void*)attn_mfma,
                        hipFuncAttributeMaxDynamicSharedMemorySize, (int)ATTN_LDS);
    attn_mfma<<<dim3(16, 16, 4), 256, ATTN_LDS, stream>>>(qkvb, yb);

    // out = y @ w_proj   (fp32 out)
    gemm_bt<false><<<dim3(8, 64), 256, 0, stream>>>(yb, wpT, out, 8192, 1024, 1024);
}